// Round 5
// baseline (148.243 us; speedup 1.0000x reference)
//
#include <hip/hip_runtime.h>
#include <stdint.h>

typedef float f32x4 __attribute__((ext_vector_type(4)));
typedef __bf16 bf16x8 __attribute__((ext_vector_type(8)));
typedef unsigned short u16x8 __attribute__((ext_vector_type(8)));

// problem sizes
#define NIMG 32
#define CIN  256
#define HWIN 3136      // 56*56
#define COUT 256
#define HWOUT 2916     // 54*54
#define NPOS 93312     // 32*2916 = 729*128

// workspace layout
#define XT_BYTES   ((size_t)NIMG*HWIN*CIN*2)            // 51,380,224
#define WT_OFF     (XT_BYTES + 8192)
#define WT_BYTES   ((size_t)36*256*64*2)                // 1,179,648
#define WS_NEED    (WT_OFF + WT_BYTES)

static __device__ __forceinline__ unsigned short f2bf(float f) {
    union { float f; uint32_t u; } v; v.f = f;
    return (unsigned short)((v.u + 0x7FFFu + ((v.u >> 16) & 1u)) >> 16);
}

static __device__ __forceinline__ void gload16(const void* g, void* l) {
    __builtin_amdgcn_global_load_lds(
        (const __attribute__((address_space(1))) void*)g,
        (__attribute__((address_space(3))) void*)l, 16, 0, 0);
}

static __device__ __forceinline__ uint32_t lds_a(const void* p) {
    return (uint32_t)(uintptr_t)(__attribute__((address_space(3))) const void*)p;
}

static __device__ __forceinline__ u16x8 ldsr(uint32_t addr) {
    u16x8 r;
    asm volatile("ds_read_b128 %0, %1" : "=v"(r) : "v"(addr));
    return r;
}

#define BAR()   __builtin_amdgcn_s_barrier()
#define SCB()   __builtin_amdgcn_sched_barrier(0)
#define LGKM0() do { asm volatile("s_waitcnt lgkmcnt(0)" ::: "memory"); SCB(); } while (0)
#define VM0()   asm volatile("s_waitcnt vmcnt(0)" ::: "memory")
#define PRIO1() __builtin_amdgcn_s_setprio(1)
#define PRIO0() __builtin_amdgcn_s_setprio(0)

#define MF(a_, b_, c_) __builtin_amdgcn_mfma_f32_16x16x32_bf16( \
    __builtin_bit_cast(bf16x8, a_), __builtin_bit_cast(bf16x8, b_), c_, 0, 0, 0)

// 16 independent MFMA (distinct acc) for one k-half
#define CLUSTER(A0_, A1_, A2_, A3_, B0_, B1_, B2_, B3_) do {                       \
    acc[0][0]=MF(A0_,B0_,acc[0][0]); acc[1][0]=MF(A1_,B0_,acc[1][0]);              \
    acc[2][0]=MF(A2_,B0_,acc[2][0]); acc[3][0]=MF(A3_,B0_,acc[3][0]);              \
    acc[0][1]=MF(A0_,B1_,acc[0][1]); acc[1][1]=MF(A1_,B1_,acc[1][1]);              \
    acc[2][1]=MF(A2_,B1_,acc[2][1]); acc[3][1]=MF(A3_,B1_,acc[3][1]);              \
    acc[0][2]=MF(A0_,B2_,acc[0][2]); acc[1][2]=MF(A1_,B2_,acc[1][2]);              \
    acc[2][2]=MF(A2_,B2_,acc[2][2]); acc[3][2]=MF(A3_,B2_,acc[3][2]);              \
    acc[0][3]=MF(A0_,B3_,acc[0][3]); acc[1][3]=MF(A1_,B3_,acc[1][3]);              \
    acc[2][3]=MF(A2_,B3_,acc[2][3]); acc[3][3]=MF(A3_,B3_,acc[3][3]);              \
} while (0)

#define RD8(A0_, A1_, A2_, A3_, B0_, B1_, B2_, B3_, base_, ck_) do {               \
    A0_ = ldsr((base_) + ar0 + (ck_)); A1_ = ldsr((base_) + ar1 + (ck_));          \
    A2_ = ldsr((base_) + ar2 + (ck_)); A3_ = ldsr((base_) + ar3 + (ck_));          \
    B0_ = ldsr((base_) + br0 + (ck_)); B1_ = ldsr((base_) + br1 + (ck_));          \
    B2_ = ldsr((base_) + br2 + (ck_)); B3_ = ldsr((base_) + br3 + (ck_));          \
} while (0)

// ---- W transform: [o][c][3][3] f32 -> bf16 +-1, blocked [kt=k9*4+cc][256 o][64 c]
__global__ void wxform(const float* __restrict__ W, unsigned short* __restrict__ Wt) {
    int idx = blockIdx.x * 256 + threadIdx.x;   // 589824 total
    int c6 = idx & 63;
    int o  = (idx >> 6) & 255;
    int cc = (idx >> 14) & 3;
    int k9 = idx >> 16;
    int c = cc * 64 + c6;
    float w = W[(size_t)(o * 256 + c) * 9 + k9];
    Wt[idx] = (w >= 0.0f) ? (unsigned short)0x3F80 : (unsigned short)0xBF80;
}

// ---- X transform: [n][c][56][56] f32 -> [n][hw][c] bf16 (NHWC)
__global__ void xxform(const float* __restrict__ X, unsigned short* __restrict__ Xt) {
    __shared__ float tile[32][65];
    int bid = blockIdx.x;
    int hwc = bid % 49;
    int cc  = (bid / 49) & 7;
    int n   = bid / (49 * 8);
    int hw0 = hwc * 64;
    int c0  = cc * 32;
    int t = threadIdx.x;
    {
        int c = t >> 3;
        int w = (t & 7) * 8;
        const float* src = X + (size_t)(n * CIN + c0 + c) * HWIN + hw0 + w;
        float4 a = *(const float4*)src;
        float4 b = *(const float4*)(src + 4);
        tile[c][w + 0] = a.x; tile[c][w + 1] = a.y; tile[c][w + 2] = a.z; tile[c][w + 3] = a.w;
        tile[c][w + 4] = b.x; tile[c][w + 5] = b.y; tile[c][w + 6] = b.z; tile[c][w + 7] = b.w;
    }
    __syncthreads();
    {
        int w  = t >> 2;
        int cb = (t & 3) * 8;
        u16x8 v;
        #pragma unroll
        for (int j = 0; j < 8; ++j) v[j] = f2bf(tile[cb + j][w]);
        *(u16x8*)(Xt + (size_t)(n * HWIN + hw0 + w) * 256 + c0 + cb) = v;
    }
}

// ---- frag-pipelined implicit GEMM: out[o][P] = sum_k Wb[o][k] * X[P][k]
// BM=128 (o), BN=128 (pos), BK=64; 256 thr = 4 waves (2M x 2N), wave tile 64x64
// LDS: 2 bufs x (A 16KB + B 16KB) = 64KB -> 2 blocks/CU
// Register frag sets S0/S1: ds_reads of half h+1 overlap MFMA of half h.
// One barrier + one VM0 per K-tile; stage lookahead = 1 full phase (~1600cyc > HBM lat)
__global__ __launch_bounds__(256, 2)
void bconv_gemm(const unsigned short* __restrict__ Xt,
                const unsigned short* __restrict__ Wt,
                float* __restrict__ out) {
    __shared__ __align__(16) char smem[65536];

    const int t    = threadIdx.x;
    const int wid  = t >> 6;
    const int lane = t & 63;
    const int l15  = lane & 15;
    const int lg   = lane >> 4;
    const int wr   = wid >> 1;       // 0..1 (M)
    const int wc   = wid & 1;        // 0..1 (N)
    const int ob   = blockIdx.x;     // 0..1 (o block)
    const uint32_t P0 = blockIdx.y * 128u;

    // staging constants (XOR swizzle baked into the GLOBAL source column)
    const uint32_t colxB = (uint32_t)(((t & 7) ^ ((t >> 3) & 7)) << 4);  // bytes
    const uint32_t rowt  = (uint32_t)(t >> 3);                           // 0..31

    // A per-thread byte base: panel row (r*32 + rowt), swizzled col
    const char* pA0 = (const char*)Wt + (size_t)ob * 16384 + rowt * 128 + colxB;

    // B gather byte bases: 4 rows per thread (r*32 + rowt)
    const char* bB[4];
    #pragma unroll
    for (int r = 0; r < 4; ++r) {
        uint32_t pos = P0 + (uint32_t)(r * 32) + rowt;
        uint32_t ni = pos / (uint32_t)HWOUT;
        uint32_t rm = pos - ni * HWOUT;
        uint32_t ph = rm / 54u;
        uint32_t pw = rm - ph * 54u;
        bB[r] = (const char*)Xt + (size_t)(ni * HWIN + ph * 56u + pw) * 512 + colxB;
    }

    // ds_read offsets (swizzled read side)
    const uint32_t x7  = (uint32_t)(l15 & 7);
    const uint32_t ck0 = ((((uint32_t)lg) ^ x7) << 4);
    const uint32_t ck1 = (((4u | (uint32_t)lg) ^ x7) << 4);
    const uint32_t ar0 = (uint32_t)(wr * 64 + 0 * 16 + l15) * 128u;
    const uint32_t ar1 = (uint32_t)(wr * 64 + 1 * 16 + l15) * 128u;
    const uint32_t ar2 = (uint32_t)(wr * 64 + 2 * 16 + l15) * 128u;
    const uint32_t ar3 = (uint32_t)(wr * 64 + 3 * 16 + l15) * 128u;
    const uint32_t br0 = 16384u + (uint32_t)(wc * 64 + 0 * 16 + l15) * 128u;
    const uint32_t br1 = 16384u + (uint32_t)(wc * 64 + 1 * 16 + l15) * 128u;
    const uint32_t br2 = 16384u + (uint32_t)(wc * 64 + 2 * 16 + l15) * 128u;
    const uint32_t br3 = 16384u + (uint32_t)(wc * 64 + 3 * 16 + l15) * 128u;

    const uint32_t E = lds_a(smem);
    const uint32_t O = E + 32768u;

    f32x4 acc[4][4];
    #pragma unroll
    for (int m = 0; m < 4; ++m)
        #pragma unroll
        for (int n = 0; n < 4; ++n)
            acc[m][n] = (f32x4){0.f, 0.f, 0.f, 0.f};

    auto STAGE = [&](uint32_t off, int kt, uint32_t kof) {
        const char* p = pA0 + (uint32_t)kt * 32768u;
        #pragma unroll
        for (int r = 0; r < 4; ++r)
            gload16(p + r * 4096, smem + off + r * 4096 + (size_t)t * 16);
        #pragma unroll
        for (int r = 0; r < 4; ++r)
            gload16(bB[r] + kof, smem + off + 16384 + r * 4096 + (size_t)t * 16);
    };

    // k-offset tracker for tile kt+2: koff = khw*512 + cc*128
    uint32_t cc2 = 2, k32 = 0, koff2 = 256;

    // prologue: tile 0 -> E, tile 1 -> O; certify 0 and 1
    STAGE(0u, 0, 0u);
    STAGE(32768u, 1, 128u);
    VM0();
    BAR();
    SCB();

    u16x8 s0a0, s0a1, s0a2, s0a3, s0b0, s0b1, s0b2, s0b3;
    u16x8 s1a0, s1a1, s1a2, s1a3, s1b0, s1b1, s1b2, s1b3;

    // preload S0 = (tile 0, half 0) from E
    RD8(s0a0, s0a1, s0a2, s0a3, s0b0, s0b1, s0b2, s0b3, E, ck0);
    LGKM0();

    for (int kt = 0; kt < 36; ++kt) {
        const uint32_t cur = (kt & 1) ? O : E;
        const uint32_t nxt = (kt & 1) ? E : O;

        // issue S1 <- (kt, half1) from cur; MFMA S0 overlaps the reads
        RD8(s1a0, s1a1, s1a2, s1a3, s1b0, s1b1, s1b2, s1b3, cur, ck1);
        SCB();
        PRIO1();
        CLUSTER(s0a0, s0a1, s0a2, s0a3, s0b0, s0b1, s0b2, s0b3);
        PRIO0();
        LGKM0();    // S1 ready; all my reads of cur drained (write-after-read safe)
        VM0();      // my stage(kt+1) loads retired (issued a full phase ago)
        BAR();      // => globally: tile kt reads done, tile kt+1 certified
        SCB();
        if (kt < 34) {
            STAGE(cur, kt + 2, koff2);
            if (cc2 == 3) { cc2 = 0; koff2 += ((k32 == 2) ? 54u : 1u) * 512u - 384u; k32 = (k32 == 2) ? 0u : k32 + 1u; }
            else          { cc2++; koff2 += 128u; }
        }
        if (kt < 35) {
            // issue S0 <- (kt+1, half0) from nxt; MFMA S1 overlaps
            RD8(s0a0, s0a1, s0a2, s0a3, s0b0, s0b1, s0b2, s0b3, nxt, ck0);
            SCB();
            PRIO1();
            CLUSTER(s1a0, s1a1, s1a2, s1a3, s1b0, s1b1, s1b2, s1b3);
            PRIO0();
            LGKM0();
        } else {
            PRIO1();
            CLUSTER(s1a0, s1a1, s1a2, s1a3, s1b0, s1b1, s1b2, s1b3);
            PRIO0();
        }
    }

    // epilogue: C/D col = l15 -> P, row = lg*4+r -> o   (93312 = 729*128 exact)
    const int orow0 = ob * 128 + wr * 64;
    #pragma unroll
    for (int n = 0; n < 4; ++n) {
        uint32_t P = P0 + (uint32_t)(wc * 64 + n * 16 + l15);
        uint32_t ni = P / (uint32_t)HWOUT;
        uint32_t rm = P - ni * HWOUT;
        float* ob_ = out + (size_t)(ni * 256u + orow0) * HWOUT + rm;
        #pragma unroll
        for (int m = 0; m < 4; ++m)
            #pragma unroll
            for (int r = 0; r < 4; ++r)
                ob_[(size_t)(m * 16 + lg * 4 + r) * HWOUT] = acc[m][n][r];
    }
}

// ---- slow correct fallback (only if ws too small)
__global__ void bconv_fallback(const float* __restrict__ X, const float* __restrict__ W,
                               float* __restrict__ out) {
    size_t idx = (size_t)blockIdx.x * 256 + threadIdx.x;
    int ow = (int)(idx % 54);
    int oh = (int)((idx / 54) % 54);
    int o  = (int)((idx / 2916) % 256);
    int n  = (int)(idx / 746496);
    float s = 0.f;
    for (int c = 0; c < 256; ++c) {
        const float* xr = X + ((size_t)(n * 256 + c) * 56 + oh) * 56 + ow;
        const float* wr = W + (size_t)(o * 256 + c) * 9;
        #pragma unroll
        for (int kh = 0; kh < 3; ++kh)
            #pragma unroll
            for (int kw = 0; kw < 3; ++kw) {
                float w = wr[kh * 3 + kw];
                float x = xr[kh * 56 + kw];
                s += (w >= 0.f) ? x : -x;
            }
    }
    out[idx] = s;
}

extern "C" void kernel_launch(void* const* d_in, const int* in_sizes, int n_in,
                              void* d_out, int out_size, void* d_ws, size_t ws_size,
                              hipStream_t stream) {
    const float* X = (const float*)d_in[0];
    const float* W = (const float*)d_in[1];
    float* out = (float*)d_out;

    if (ws_size < WS_NEED) {
        bconv_fallback<<<93312, 256, 0, stream>>>(X, W, out);
        return;
    }
    unsigned short* Xt = (unsigned short*)d_ws;
    unsigned short* Wt = (unsigned short*)((char*)d_ws + WT_OFF);

    wxform<<<2304, 256, 0, stream>>>(W, Wt);
    xxform<<<12544, 256, 0, stream>>>(X, Xt);

    dim3 grid(2, 729);
    bconv_gemm<<<grid, 256, 0, stream>>>(Xt, Wt, out);
}